// Round 1
// baseline (254.924 us; speedup 1.0000x reference)
//
#include <hip/hip_runtime.h>

typedef _Float16 f16;
typedef __attribute__((ext_vector_type(8))) _Float16 f16x8;
typedef __attribute__((ext_vector_type(4))) float f32x4;

#define H_ 128
#define W_ 128
#define B_ 2

// ---------------- weight packing: OIHW fp32 -> [tap][Opad][C] f16 ----------
__global__ void pack_w_k(const float* __restrict__ src, f16* __restrict__ dst,
                         int O, int C, int Opad, int total) {
  int d = blockIdx.x * 256 + threadIdx.x;
  if (d >= total) return;
  int ci = d % C;
  int rest = d / C;
  int o = rest % Opad;
  int t = rest / Opad;
  float v = (o < O) ? src[((size_t)o * C + ci) * 9 + t] : 0.f;
  dst[d] = (f16)v;
}

// ------------- NCHW fp32 (x, ref) -> NHWC f16 concat (256 ch) --------------
__global__ __launch_bounds__(256) void to_nhwc_k(const float* __restrict__ x,
                                                 const float* __restrict__ ref,
                                                 f16* __restrict__ featB) {
  int row = blockIdx.x;  // b*H + h
  int b = row >> 7, h = row & 127;
  int w0 = blockIdx.y * 64;
  int chunk = blockIdx.z;  // 0..7 -> 32 output channels each
  const float* src = (chunk < 4) ? x : ref;
  int c0 = (chunk & 3) * 32;
  __shared__ __align__(16) f16 T[64][40];  // [w][c], stride 40 f16 = 80B (16B mult)
  int tid = threadIdx.x;
#pragma unroll
  for (int i = 0; i < 2; ++i) {
    int idx = tid + i * 256;
    int c = idx >> 4, g = idx & 15;  // g*4 = w offset
    const float4 v = *(const float4*)(src + (((size_t)(b * 128 + c0 + c)) * H_ + h) * W_ + w0 + g * 4);
    T[g * 4 + 0][c] = (f16)v.x;
    T[g * 4 + 1][c] = (f16)v.y;
    T[g * 4 + 2][c] = (f16)v.z;
    T[g * 4 + 3][c] = (f16)v.w;
  }
  __syncthreads();
  int w = tid >> 2, g = tid & 3;
  f16x8 o = *(const f16x8*)&T[w][g * 8];
  *(f16x8*)(featB + ((size_t)row * W_ + w0 + w) * 256 + chunk * 32 + g * 8) = o;
}

// ---------------- implicit-GEMM 3x3 conv, N-tile=64, f16 MFMA --------------
// src: NHWC f16 [B,H,W,CIN]; Wp: [9][128][CIN] f16; dst: NHWC f16 [B,H,W,128]
template <int CIN, bool RELU>
__global__ __launch_bounds__(256, 2) void conv_gemm_k(const f16* __restrict__ src,
                                                      const f16* __restrict__ Wp,
                                                      f16* __restrict__ dst) {
  const int row = blockIdx.x;  // b*H + h : M-tile = one image row (128 px)
  const int nb = blockIdx.y;   // o-base = nb*64
  const int b = row >> 7, h = row & 127;
  __shared__ __align__(16) f16 As[128][32];  // [pixel][k]
  __shared__ __align__(16) f16 Bs[64][32];   // [o][k]
  const int tid = threadIdx.x;
  const int lane = tid & 63, wave = tid >> 6;
  const int wm = wave >> 1, wn = wave & 1;  // wave covers m:64 x n:32
  const int l16 = lane & 15, quad = lane >> 4;
  f32x4 acc[4][2] = {};
  for (int t = 0; t < 9; ++t) {
    const int ky = t / 3 - 1, kx = t % 3 - 1;
    const int y = h + ky;
    const bool yok = (unsigned)y < (unsigned)H_;
    const f16* srow = src + (size_t)(b * H_ + y) * W_ * CIN;
    const f16* wt = Wp + ((size_t)t * 128 + nb * 64) * CIN;
    for (int cc = 0; cc < CIN / 32; ++cc) {
      const int c0 = cc * 32;
      __syncthreads();
#pragma unroll
      for (int i = 0; i < 2; ++i) {  // stage A: 128px x 32k, 16B/thread/iter
        int idx = tid + i * 256;
        int m = idx >> 2, g = idx & 3;
        int xw = m + kx;
        f16x8 v = {};
        if (yok && (unsigned)xw < (unsigned)W_)
          v = *(const f16x8*)(srow + (size_t)xw * CIN + c0 + g * 8);
        *(f16x8*)&As[m][g * 8] = v;
      }
      {  // stage B: 64o x 32k
        int o = tid >> 2, g = tid & 3;
        *(f16x8*)&Bs[o][g * 8] = *(const f16x8*)(wt + (size_t)o * CIN + c0 + g * 8);
      }
      __syncthreads();
      f16x8 af[4], bf[2];
#pragma unroll
      for (int i = 0; i < 4; ++i)
        af[i] = *(const f16x8*)&As[wm * 64 + i * 16 + l16][quad * 8];
#pragma unroll
      for (int j = 0; j < 2; ++j)
        bf[j] = *(const f16x8*)&Bs[wn * 32 + j * 16 + l16][quad * 8];
#pragma unroll
      for (int i = 0; i < 4; ++i)
#pragma unroll
        for (int j = 0; j < 2; ++j)
          acc[i][j] = __builtin_amdgcn_mfma_f32_16x16x32_f16(af[i], bf[j], acc[i][j], 0, 0, 0);
    }
  }
  const size_t pixbase = (size_t)row * W_;
#pragma unroll
  for (int i = 0; i < 4; ++i) {
    int m0 = wm * 64 + i * 16 + quad * 4;
#pragma unroll
    for (int j = 0; j < 2; ++j) {
      int o = nb * 64 + wn * 32 + j * 16 + l16;
#pragma unroll
      for (int r = 0; r < 4; ++r) {
        float v = acc[i][j][r];
        if (RELU) v = fmaxf(v, 0.f);
        dst[(pixbase + m0 + r) * 128 + o] = (f16)v;
      }
    }
  }
}

// ---------------- offset conv: N=32 (18 real, zero-padded), fp32 out -------
__global__ __launch_bounds__(256, 2) void conv_off_k(const f16* __restrict__ src,
                                                     const f16* __restrict__ Wp,
                                                     float* __restrict__ dst) {
  const int row = blockIdx.x;
  const int b = row >> 7, h = row & 127;
  __shared__ __align__(16) f16 As[128][32];
  __shared__ __align__(16) f16 Bs[32][32];
  const int tid = threadIdx.x;
  const int lane = tid & 63, wave = tid >> 6;  // wave covers m:32 x n:32
  const int l16 = lane & 15, quad = lane >> 4;
  f32x4 acc[2][2] = {};
  for (int t = 0; t < 9; ++t) {
    const int ky = t / 3 - 1, kx = t % 3 - 1;
    const int y = h + ky;
    const bool yok = (unsigned)y < (unsigned)H_;
    const f16* srow = src + (size_t)(b * H_ + y) * W_ * 128;
    const f16* wt = Wp + (size_t)t * 32 * 128;
    for (int cc = 0; cc < 4; ++cc) {
      const int c0 = cc * 32;
      __syncthreads();
#pragma unroll
      for (int i = 0; i < 2; ++i) {
        int idx = tid + i * 256;
        int m = idx >> 2, g = idx & 3;
        int xw = m + kx;
        f16x8 v = {};
        if (yok && (unsigned)xw < (unsigned)W_)
          v = *(const f16x8*)(srow + (size_t)xw * 128 + c0 + g * 8);
        *(f16x8*)&As[m][g * 8] = v;
      }
      if (tid < 128) {
        int o = tid >> 2, g = tid & 3;
        *(f16x8*)&Bs[o][g * 8] = *(const f16x8*)(wt + (size_t)o * 128 + c0 + g * 8);
      }
      __syncthreads();
      f16x8 af[2], bf[2];
#pragma unroll
      for (int i = 0; i < 2; ++i)
        af[i] = *(const f16x8*)&As[wave * 32 + i * 16 + l16][quad * 8];
#pragma unroll
      for (int j = 0; j < 2; ++j)
        bf[j] = *(const f16x8*)&Bs[j * 16 + l16][quad * 8];
#pragma unroll
      for (int i = 0; i < 2; ++i)
#pragma unroll
        for (int j = 0; j < 2; ++j)
          acc[i][j] = __builtin_amdgcn_mfma_f32_16x16x32_f16(af[i], bf[j], acc[i][j], 0, 0, 0);
    }
  }
  const size_t pixbase = (size_t)row * W_;
#pragma unroll
  for (int i = 0; i < 2; ++i)
#pragma unroll
    for (int j = 0; j < 2; ++j)
#pragma unroll
      for (int r = 0; r < 4; ++r) {
        int m = wave * 32 + i * 16 + quad * 4 + r;
        int o = j * 16 + l16;
        dst[(pixbase + m) * 32 + o] = acc[i][j][r];
      }
}

// ------- deformable conv: fused bilinear sampling + implicit GEMM ----------
// featB: NHWC f16 256ch (ref channels at +128); off: [pix][32] fp32;
// Wp: [9][128][128] f16; out: NCHW fp32. A = weights (m=o), B = patches (n=pix).
__global__ __launch_bounds__(256, 2) void deform_k(const f16* __restrict__ featB,
                                                   const float* __restrict__ off,
                                                   const f16* __restrict__ Wp,
                                                   float* __restrict__ out) {
  const int row = blockIdx.x;  // b*H + h : pixel tile = one row (128 px)
  const int ob = blockIdx.y;   // o-base = ob*64
  const int b = row >> 7, h = row & 127;
  __shared__ __align__(16) f16 Ws[64][32];   // [o][k]
  __shared__ __align__(16) f16 Ss[128][32];  // [pixel][k] sampled
  __shared__ int my0[9][128];
  __shared__ int mx0[9][128];
  __shared__ float mwy[9][128];
  __shared__ float mwx[9][128];
  const int tid = threadIdx.x;
  const int lane = tid & 63, wave = tid >> 6;
  const int wo = wave >> 1, wp = wave & 1;  // wave covers o:32 x pix:64
  const int l16 = lane & 15, quad = lane >> 4;
  // bilinear meta for all 9 taps, once
  for (int idx = tid; idx < 9 * 128; idx += 256) {
    int t = idx >> 7, m = idx & 127;
    const float2 d = *(const float2*)(off + ((size_t)row * W_ + m) * 32 + 2 * t);
    float py = (float)(h + t / 3 - 1) + d.x;
    float px = (float)(m + t % 3 - 1) + d.y;
    float fy = floorf(py), fx = floorf(px);
    my0[t][m] = (int)fy;
    mx0[t][m] = (int)fx;
    mwy[t][m] = py - fy;
    mwx[t][m] = px - fx;
  }
  f32x4 acc[2][4] = {};
  for (int t = 0; t < 9; ++t) {
    const f16* wt = Wp + ((size_t)t * 128 + ob * 64) * 128;
    for (int cc = 0; cc < 4; ++cc) {
      const int c0 = cc * 32;
      __syncthreads();  // also covers meta-fill before first use
#pragma unroll
      for (int i = 0; i < 2; ++i) {  // stage sampled patches
        int idx = tid + i * 256;
        int m = idx >> 2, g = idx & 3;
        int y0 = my0[t][m], x0 = mx0[t][m];
        float wy = mwy[t][m], wx = mwx[t][m];
        const f16* base = featB + 128 + c0 + g * 8;  // ref channels
        f16x8 v00 = {}, v01 = {}, v10 = {}, v11 = {};
        bool y0ok = (unsigned)y0 < (unsigned)H_;
        bool y1ok = (unsigned)(y0 + 1) < (unsigned)H_;
        bool x0ok = (unsigned)x0 < (unsigned)W_;
        bool x1ok = (unsigned)(x0 + 1) < (unsigned)W_;
        const f16* r0 = base + (size_t)(b * H_ + y0) * W_ * 256;
        const f16* r1 = r0 + (size_t)W_ * 256;
        if (y0ok && x0ok) v00 = *(const f16x8*)(r0 + (size_t)x0 * 256);
        if (y0ok && x1ok) v01 = *(const f16x8*)(r0 + (size_t)(x0 + 1) * 256);
        if (y1ok && x0ok) v10 = *(const f16x8*)(r1 + (size_t)x0 * 256);
        if (y1ok && x1ok) v11 = *(const f16x8*)(r1 + (size_t)(x0 + 1) * 256);
        float w00 = (1.f - wy) * (1.f - wx), w01 = (1.f - wy) * wx;
        float w10 = wy * (1.f - wx), w11 = wy * wx;
        f16x8 res;
#pragma unroll
        for (int k = 0; k < 8; ++k) {
          float v = w00 * (float)v00[k] + w01 * (float)v01[k] +
                    w10 * (float)v10[k] + w11 * (float)v11[k];
          res[k] = (f16)v;
        }
        *(f16x8*)&Ss[m][g * 8] = res;
      }
      {  // stage weights
        int o = tid >> 2, g = tid & 3;
        *(f16x8*)&Ws[o][g * 8] = *(const f16x8*)(wt + (size_t)o * 128 + c0 + g * 8);
      }
      __syncthreads();
      f16x8 af[2], bf[4];
#pragma unroll
      for (int i = 0; i < 2; ++i)
        af[i] = *(const f16x8*)&Ws[wo * 32 + i * 16 + l16][quad * 8];
#pragma unroll
      for (int j = 0; j < 4; ++j)
        bf[j] = *(const f16x8*)&Ss[wp * 64 + j * 16 + l16][quad * 8];
#pragma unroll
      for (int i = 0; i < 2; ++i)
#pragma unroll
        for (int j = 0; j < 4; ++j)
          acc[i][j] = __builtin_amdgcn_mfma_f32_16x16x32_f16(af[i], bf[j], acc[i][j], 0, 0, 0);
    }
  }
#pragma unroll
  for (int i = 0; i < 2; ++i)
#pragma unroll
    for (int r = 0; r < 4; ++r) {
      int o = ob * 64 + wo * 32 + i * 16 + quad * 4 + r;
#pragma unroll
      for (int j = 0; j < 4; ++j) {
        int w = wp * 64 + j * 16 + l16;
        out[((size_t)(b * 128 + o) * H_ + h) * W_ + w] = acc[i][j][r];
      }
    }
}

extern "C" void kernel_launch(void* const* d_in, const int* in_sizes, int n_in,
                              void* d_out, int out_size, void* d_ws, size_t ws_size,
                              hipStream_t stream) {
  const float* x = (const float*)d_in[0];
  const float* ref = (const float*)d_in[1];
  const float* w1 = (const float*)d_in[2];
  const float* w2 = (const float*)d_in[3];
  const float* woff = (const float*)d_in[4];
  const float* wdef = (const float*)d_in[5];
  float* out = (float*)d_out;
  char* ws = (char*)d_ws;
  // workspace layout (total ~39 MB)
  f16* featB = (f16*)ws;                 // 16,777,216 B : NHWC f16 concat 256ch
  f16* est1 = (f16*)(ws + 16777216);     //  8,388,608 B
  f16* est2 = (f16*)(ws + 25165824);     //  8,388,608 B
  float* offb = (float*)(ws + 33554432); //  4,194,304 B : [pix][32] fp32
  f16* W1p = (f16*)(ws + 37748736);      //    589,824 B
  f16* W2p = (f16*)(ws + 38338560);      //    294,912 B
  f16* Woffp = (f16*)(ws + 38633472);    //     73,728 B
  f16* Wdefp = (f16*)(ws + 38707200);    //    294,912 B

  pack_w_k<<<dim3(294912 / 256), 256, 0, stream>>>(w1, W1p, 128, 256, 128, 294912);
  pack_w_k<<<dim3(147456 / 256), 256, 0, stream>>>(w2, W2p, 128, 128, 128, 147456);
  pack_w_k<<<dim3(36864 / 256), 256, 0, stream>>>(woff, Woffp, 18, 128, 32, 36864);
  pack_w_k<<<dim3(147456 / 256), 256, 0, stream>>>(wdef, Wdefp, 128, 128, 128, 147456);
  to_nhwc_k<<<dim3(256, 2, 8), 256, 0, stream>>>(x, ref, featB);
  conv_gemm_k<256, true><<<dim3(256, 2), 256, 0, stream>>>(featB, W1p, est1);
  conv_gemm_k<128, true><<<dim3(256, 2), 256, 0, stream>>>(est1, W2p, est2);
  conv_off_k<<<dim3(256), 256, 0, stream>>>(est2, Woffp, offb);
  deform_k<<<dim3(256, 2), 256, 0, stream>>>(featB, offb, Wdefp, out);
}

// Round 2
// 183.322 us; speedup vs baseline: 1.3906x; 1.3906x over previous
//
#include <hip/hip_runtime.h>

typedef _Float16 f16;
typedef __attribute__((ext_vector_type(8))) _Float16 f16x8;
typedef __attribute__((ext_vector_type(4))) float f32x4;

#define H_ 128
#define W_ 128

// padded spatial layout: [b][y][x][C] with y,x in 0..129, zero halo at 0 and 129.

__device__ __forceinline__ void g2l16(const void* g, void* l) {
  __builtin_amdgcn_global_load_lds((const __attribute__((address_space(1))) void*)g,
                                   (__attribute__((address_space(3))) void*)l, 16, 0, 0);
}

// ---------------- prep: weight packing (swizzle baked) + halo zeroing -------
// conv pack layout: [ky][cc][nb][kx][NT][32], slot-chunk g holds source chunk g^((o>>1)&3)
__device__ __forceinline__ void pack_conv(const float* __restrict__ src, f16* __restrict__ dst,
                                          long idx, int C, int NT, int NB, int O) {
  int ci3 = idx & 7;
  int g = (idx >> 3) & 3;
  long t1 = idx >> 5;
  int o = t1 % NT;  long t2 = t1 / NT;
  int kx = t2 % 3;  long t3 = t2 / 3;
  int nb = t3 % NB; long t4 = t3 / NB;
  int nkc = C >> 5;
  int cc = t4 % nkc;
  int ky = t4 / nkc;
  int oo = nb * NT + o;
  int c = (cc << 5) + ((g ^ ((o >> 1) & 3)) << 3) + ci3;
  float v = (oo < O) ? src[(((size_t)oo * C + c) * 3 + ky) * 3 + kx] : 0.f;
  dst[idx] = (f16)v;
}

__device__ __forceinline__ void halo_zero(f16* __restrict__ buf, long e, int C) {
  int c = e & (C - 1);
  long t = e / C;
  int b = (int)(t / 516);
  int p = (int)(t % 516);
  int y, x;
  if (p < 130)      { y = 0;   x = p; }
  else if (p < 260) { y = 129; x = p - 130; }
  else if (p < 388) { x = 0;   y = p - 259; }
  else              { x = 129; y = p - 387; }
  buf[((size_t)(b * 130 + y) * 130 + x) * C + c] = (f16)0.f;
}

__global__ __launch_bounds__(256) void prep_k(const float* __restrict__ w1, const float* __restrict__ w2,
                                              const float* __restrict__ woff, const float* __restrict__ wdef,
                                              f16* __restrict__ W1p, f16* __restrict__ W2p,
                                              f16* __restrict__ Woffp, f16* __restrict__ Wdefp,
                                              f16* __restrict__ featB, f16* __restrict__ est1,
                                              f16* __restrict__ est2) {
  long idx = (long)blockIdx.x * 256 + threadIdx.x;
  if (idx < 294912) { pack_conv(w1, W1p, idx, 256, 64, 2, 128); return; }
  idx -= 294912;
  if (idx < 147456) { pack_conv(w2, W2p, idx, 128, 64, 2, 128); return; }
  idx -= 147456;
  if (idx < 36864) { pack_conv(woff, Woffp, idx, 128, 32, 1, 18); return; }
  idx -= 36864;
  if (idx < 147456) {  // deform pack: [t][o][slot g] <- chunk g^(o&7)
    int ci3 = idx & 7;
    int g = (idx >> 3) & 15;
    int o = (idx >> 7) & 127;
    int t = (int)(idx >> 14);
    int c = ((g ^ (o & 7)) << 3) + ci3;
    Wdefp[idx] = (f16)wdef[(((size_t)o * 128 + c) * 3 + t / 3) * 3 + t % 3];
    return;
  }
  idx -= 147456;
  if (idx < 264192) { halo_zero(featB, idx, 256); return; }
  idx -= 264192;
  if (idx < 132096) { halo_zero(est1, idx, 128); return; }
  idx -= 132096;
  if (idx < 132096) halo_zero(est2, idx, 128);
}

// ------------- NCHW fp32 (x, ref) -> padded NHWC f16 concat (256 ch) -------
__global__ __launch_bounds__(256) void to_nhwc_k(const float* __restrict__ x,
                                                 const float* __restrict__ ref,
                                                 f16* __restrict__ featB) {
  int row = blockIdx.x;  // b*H + h
  int b = row >> 7, h = row & 127;
  int w0 = blockIdx.y * 64;
  int chunk = blockIdx.z;  // 0..7 -> 32 channels each
  const float* src = (chunk < 4) ? x : ref;
  int c0 = (chunk & 3) * 32;
  __shared__ __align__(16) f16 T[64][40];
  int tid = threadIdx.x;
#pragma unroll
  for (int i = 0; i < 2; ++i) {
    int idx = tid + i * 256;
    int c = idx >> 4, g = idx & 15;
    const float4 v = *(const float4*)(src + (((size_t)(b * 128 + c0 + c)) * H_ + h) * W_ + w0 + g * 4);
    T[g * 4 + 0][c] = (f16)v.x;
    T[g * 4 + 1][c] = (f16)v.y;
    T[g * 4 + 2][c] = (f16)v.z;
    T[g * 4 + 3][c] = (f16)v.w;
  }
  __syncthreads();
  int w = tid >> 2, g = tid & 3;
  f16x8 o = *(const f16x8*)&T[w][g * 8];
  *(f16x8*)(featB + ((size_t)(b * 130 + h + 1) * 130 + w0 + w + 1) * 256 + chunk * 32 + g * 8) = o;
}

// ---------------- implicit-GEMM 3x3 conv over padded NHWC ------------------
// One staged 130-px row serves all 3 kx taps. A/B staged with global_load_lds.
template <int CIN, int NT, bool RELU, bool F16OUT>
__global__ __launch_bounds__(256, 2) void conv_k(const f16* __restrict__ src,
                                                 const f16* __restrict__ Wp,
                                                 f16* __restrict__ dstH,
                                                 float* __restrict__ dstF) {
  const int row = blockIdx.x, nb = blockIdx.y;
  const int b = row >> 7, h = row & 127;
  constexpr int NKC = CIN / 32;
  constexpr int NB = (NT == 64) ? 2 : 1;
  __shared__ __align__(16) f16 As[130][32];
  __shared__ __align__(16) f16 Bs[3][NT][32];
  const int tid = threadIdx.x;
  const int lane = tid & 63, wave = tid >> 6;
  const int l16 = lane & 15, quad = lane >> 4;
  constexpr int MI = (NT == 64) ? 4 : 2;
  const int wmBase = (NT == 64) ? (wave >> 1) * 64 : wave * 32;
  const int wn = (NT == 64) ? (wave & 1) : 0;
  f32x4 acc[MI][2] = {};
  char* AsF = (char*)&As[0][0];
  char* BsF = (char*)&Bs[0][0][0];
  for (int ky = 0; ky < 3; ++ky) {
    const f16* abase0 = src + ((size_t)(b * 130 + h + ky) * 130) * CIN;
    for (int cc = 0; cc < NKC; ++cc) {
      __syncthreads();
      const f16* abase = abase0 + cc * 32;
      {  // stage A: 130 px x 32 k (520 chunks), per-lane source xor-permute
#pragma unroll
        for (int r = 0; r < 2; ++r) {
          int ch = r * 256 + tid;
          int x = ch >> 2, g = ch & 3;
          g2l16(abase + (size_t)x * CIN + ((g ^ ((x >> 1) & 3)) << 3), AsF + ch * 16);
        }
        if (tid < 8) {
          int ch = 512 + tid;
          int x = ch >> 2, g = ch & 3;
          g2l16(abase + (size_t)x * CIN + ((g ^ ((x >> 1) & 3)) << 3), AsF + ch * 16);
        }
      }
      {  // stage B: 3 taps x NT o x 32 k, contiguous (swizzle baked at pack)
        const f16* bbase = Wp + ((size_t)((ky * NKC + cc) * NB + nb)) * (3 * NT * 32);
        constexpr int BCH = 3 * NT * 32 / 8;
#pragma unroll
        for (int r = 0; r < BCH / 256; ++r) {
          int ch = r * 256 + tid;
          g2l16(bbase + ch * 8, BsF + ch * 16);
        }
        if constexpr (BCH % 256) {
          if (tid < BCH % 256) {
            int ch = (BCH / 256) * 256 + tid;
            g2l16(bbase + ch * 8, BsF + ch * 16);
          }
        }
      }
      __syncthreads();
#pragma unroll
      for (int kx = 0; kx < 3; ++kx) {
        f16x8 bf[2];
#pragma unroll
        for (int j = 0; j < 2; ++j) {
          int o = wn * 32 + j * 16 + l16;
          bf[j] = *(const f16x8*)&Bs[kx][o][(quad ^ ((o >> 1) & 3)) << 3];
        }
#pragma unroll
        for (int i = 0; i < MI; ++i) {
          int x = wmBase + i * 16 + l16 + kx;
          f16x8 a = *(const f16x8*)&As[x][(quad ^ ((x >> 1) & 3)) << 3];
#pragma unroll
          for (int j = 0; j < 2; ++j)
            acc[i][j] = __builtin_amdgcn_mfma_f32_16x16x32_f16(a, bf[j], acc[i][j], 0, 0, 0);
        }
      }
    }
  }
#pragma unroll
  for (int i = 0; i < MI; ++i)
#pragma unroll
    for (int j = 0; j < 2; ++j) {
      int o = nb * NT + wn * 32 + j * 16 + l16;
#pragma unroll
      for (int r = 0; r < 4; ++r) {
        int m = wmBase + i * 16 + quad * 4 + r;
        float v = acc[i][j][r];
        if (RELU) v = fmaxf(v, 0.f);
        if (F16OUT)
          dstH[((size_t)(b * 130 + h + 1) * 130 + m + 1) * 128 + o] = (f16)v;
        else
          dstF[((size_t)row * 128 + m) * 32 + o] = v;
      }
    }
}

// ------- deformable conv: per-tap full-K staging, packed-f16 blend ---------
// A = weights [o][k] (LDS Ws), B = sampled pixels [px][k] (LDS Ss).
__global__ __launch_bounds__(256, 2) void deform_k(const f16* __restrict__ featB,
                                                   const float* __restrict__ offb,
                                                   const f16* __restrict__ Wdefp,
                                                   float* __restrict__ out) {
  const int row = blockIdx.x, tile = blockIdx.y;
  const int b = row >> 7, h = row & 127;
  __shared__ __align__(16) f16 Ws[128][128];  // 32 KB, staged per tap via DMA
  __shared__ __align__(16) f16 Ss[64][128];   // 16 KB, sampled, swizzled on write
  __shared__ int4 mlds[9][64];                // bilinear meta
  const int tid = threadIdx.x;
  const int lane = tid & 63, wave = tid >> 6;
  const int l16 = lane & 15, quad = lane >> 4;
  // meta for all 9 taps x 64 px
  for (int e = tid; e < 576; e += 256) {
    int t = e >> 6, p = e & 63;
    int w = tile * 64 + p;
    const float2 d = *(const float2*)(offb + ((size_t)row * 128 + w) * 32 + 2 * t);
    float py = (float)(h + t / 3 - 1) + d.x;
    float pxf = (float)(w + t % 3 - 1) + d.y;
    float fy = floorf(py), fx = floorf(pxf);
    mlds[t][p] = make_int4((int)fy, (int)fx, __float_as_int(py - fy), __float_as_int(pxf - fx));
  }
  f32x4 acc[2][4] = {};
  const int px = tid >> 2;   // pixel within tile
  const int cgrp = tid & 3;  // 32-channel group
  char* WsF = (char*)&Ws[0][0];
  for (int t = 0; t < 9; ++t) {
    __syncthreads();
    const f16* wt = Wdefp + (size_t)t * 16384;
#pragma unroll
    for (int r = 0; r < 8; ++r) {  // Ws: 2048 chunks DMA
      int ch = r * 256 + tid;
      g2l16(wt + ch * 8, WsF + ch * 16);
    }
    {  // sample + blend 32 channels for this thread's pixel
      int4 mt = mlds[t][px];
      int iy = mt.x, ix = mt.y;
      float wy = __int_as_float(mt.z), wx = __int_as_float(mt.w);
      int yp = iy + 1, xp = ix + 1;  // padded coords
      bool y0v = (unsigned)yp < 130u, y1v = (unsigned)(yp + 1) < 130u;
      bool x0v = (unsigned)xp < 130u, x1v = (unsigned)(xp + 1) < 130u;
      int cy0 = y0v ? yp : 0, cy1 = y1v ? yp + 1 : 0;
      int cx0 = x0v ? xp : 0, cx1 = x1v ? xp + 1 : 0;
      float u0 = (1.f - wy) * (y0v ? 1.f : 0.f), u1 = wy * (y1v ? 1.f : 0.f);
      float s0 = (1.f - wx) * (x0v ? 1.f : 0.f), s1 = wx * (x1v ? 1.f : 0.f);
      f16 h00 = (f16)(u0 * s0), h01 = (f16)(u0 * s1);
      f16 h10 = (f16)(u1 * s0), h11 = (f16)(u1 * s1);
      const size_t bb = (size_t)b * 130;
      const f16* p00 = featB + ((bb + cy0) * 130 + cx0) * 256 + 128 + cgrp * 32;
      const f16* p01 = featB + ((bb + cy0) * 130 + cx1) * 256 + 128 + cgrp * 32;
      const f16* p10 = featB + ((bb + cy1) * 130 + cx0) * 256 + 128 + cgrp * 32;
      const f16* p11 = featB + ((bb + cy1) * 130 + cx1) * 256 + 128 + cgrp * 32;
      f16x8 v00[4], v01[4], v10[4], v11[4];
#pragma unroll
      for (int q = 0; q < 4; ++q) {
        v00[q] = *(const f16x8*)(p00 + q * 8);
        v01[q] = *(const f16x8*)(p01 + q * 8);
        v10[q] = *(const f16x8*)(p10 + q * 8);
        v11[q] = *(const f16x8*)(p11 + q * 8);
      }
#pragma unroll
      for (int q = 0; q < 4; ++q) {
        f16x8 rb = v00[q] * h00 + v01[q] * h01 + v10[q] * h10 + v11[q] * h11;
        int c = cgrp * 4 + q;
        *(f16x8*)&Ss[px][(c ^ (px & 7)) << 3] = rb;
      }
    }
    __syncthreads();
#pragma unroll
    for (int cc = 0; cc < 4; ++cc) {
      f16x8 af[2], bf[4];
#pragma unroll
      for (int i = 0; i < 2; ++i) {
        int o = wave * 32 + i * 16 + l16;
        af[i] = *(const f16x8*)&Ws[o][((cc * 4 + quad) ^ (o & 7)) << 3];
      }
#pragma unroll
      for (int j = 0; j < 4; ++j) {
        int p = j * 16 + l16;
        bf[j] = *(const f16x8*)&Ss[p][((cc * 4 + quad) ^ (p & 7)) << 3];
      }
#pragma unroll
      for (int i = 0; i < 2; ++i)
#pragma unroll
        for (int j = 0; j < 4; ++j)
          acc[i][j] = __builtin_amdgcn_mfma_f32_16x16x32_f16(af[i], bf[j], acc[i][j], 0, 0, 0);
    }
  }
#pragma unroll
  for (int i = 0; i < 2; ++i)
#pragma unroll
    for (int r = 0; r < 4; ++r) {
      int o = wave * 32 + i * 16 + quad * 4 + r;
#pragma unroll
      for (int j = 0; j < 4; ++j) {
        int w = tile * 64 + j * 16 + l16;
        out[((size_t)(b * 128 + o) * 128 + h) * 128 + w] = acc[i][j][r];
      }
    }
}

extern "C" void kernel_launch(void* const* d_in, const int* in_sizes, int n_in,
                              void* d_out, int out_size, void* d_ws, size_t ws_size,
                              hipStream_t stream) {
  const float* x = (const float*)d_in[0];
  const float* ref = (const float*)d_in[1];
  const float* w1 = (const float*)d_in[2];
  const float* w2 = (const float*)d_in[3];
  const float* woff = (const float*)d_in[4];
  const float* wdef = (const float*)d_in[5];
  float* out = (float*)d_out;
  char* ws = (char*)d_ws;
  // workspace layout (padded 130x130 spatial), ~40 MB
  f16* featB = (f16*)(ws + 0);          // 2*130*130*256*2 = 17,305,600
  f16* est1 = (f16*)(ws + 17305600);    // 2*130*130*128*2 =  8,652,800
  f16* est2 = (f16*)(ws + 25958400);    //                    8,652,800
  float* offb = (float*)(ws + 34611200);// 32768*32*4      =  4,194,304
  f16* W1p = (f16*)(ws + 38805504);     //   589,824
  f16* W2p = (f16*)(ws + 39395328);     //   294,912
  f16* Woffp = (f16*)(ws + 39690240);   //    73,728
  f16* Wdefp = (f16*)(ws + 39763968);   //   294,912

  prep_k<<<dim3(4512), 256, 0, stream>>>(w1, w2, woff, wdef, W1p, W2p, Woffp, Wdefp,
                                         featB, est1, est2);
  to_nhwc_k<<<dim3(256, 2, 8), 256, 0, stream>>>(x, ref, featB);
  conv_k<256, 64, true, true><<<dim3(256, 2), 256, 0, stream>>>(featB, W1p, est1, nullptr);
  conv_k<128, 64, true, true><<<dim3(256, 2), 256, 0, stream>>>(est1, W2p, est2, nullptr);
  conv_k<128, 32, false, false><<<dim3(256, 1), 256, 0, stream>>>(est2, Woffp, nullptr, offb);
  deform_k<<<dim3(256, 2), 256, 0, stream>>>(featB, offb, Wdefp, out);
}